// Round 4
// baseline (117.425 us; speedup 1.0000x reference)
//
#include <hip/hip_runtime.h>
#include <hip/hip_bf16.h>
#include <math.h>

#define Bsz 8
#define Nn  2048
#define Ff  256

typedef short short8 __attribute__((ext_vector_type(8)));
typedef float f32x4  __attribute__((ext_vector_type(4)));
typedef unsigned short u16x4 __attribute__((ext_vector_type(4)));

static __device__ __forceinline__ unsigned short f2bf(float v) {
    __hip_bfloat16 b = __float2bfloat16(v);
    return *reinterpret_cast<unsigned short*>(&b);
}
static __device__ __forceinline__ float fast_rcp(float x) {
    return __builtin_amdgcn_rcpf(x);
}

// ---------------- k_pre: mg[i][j] = {mask, g}; gmax[i] = max_j g -----------------
// one block per row i; 256 thr x 8 elems
__global__ __launch_bounds__(256) void k_pre(const float* __restrict__ Ageo,
                                             const float* __restrict__ Dm,
                                             const float* __restrict__ thr_p,
                                             float2* __restrict__ mg,
                                             float* __restrict__ gmax) {
    const int i   = blockIdx.x;
    const int tid = threadIdx.x;
    const int j0  = tid * 8;
    const float c10 = 10.0f * thr_p[0];
    float m = 0.0f;
    float mo[8], go[8];
#pragma unroll
    for (int p = 0; p < 2; p++) {
        float4 a = *(const float4*)&Ageo[(size_t)i * Nn + j0 + p * 4];
        float4 d = *(const float4*)&Dm[(size_t)i * Nn + j0 + p * 4];
        float av[4] = {a.x, a.y, a.z, a.w};
        float dv[4] = {d.x, d.y, d.z, d.w};
#pragma unroll
        for (int c = 0; c < 4; c++) {
            int j = j0 + p * 4 + c;
            float dd = (j == i) ? 1.0f : dv[c];
            float mk = fast_rcp(1.0f + __expf(c10 - 10.0f * av[c]));
            float gg = mk * fast_rcp(dd + 1e-5f);
            mo[p * 4 + c] = mk;
            go[p * 4 + c] = gg;
            m = fmaxf(m, gg);
        }
    }
    float4* dst = (float4*)&mg[(size_t)i * Nn + j0];
#pragma unroll
    for (int p = 0; p < 4; p++)
        dst[p] = make_float4(mo[p * 2], go[p * 2], mo[p * 2 + 1], go[p * 2 + 1]);

#pragma unroll
    for (int d = 32; d; d >>= 1) m = fmaxf(m, __shfl_xor(m, d));
    __shared__ float red[4];
    if ((tid & 63) == 0) red[tid >> 6] = m;
    __syncthreads();
    if (tid == 0) gmax[i] = fmaxf(fmaxf(red[0], red[1]), fmaxf(red[2], red[3]));
}

// ---------------- k_h: MFMA bf16  h = X@W^T + b -> hT (B,F,N) bf16 ; s1 ; s2 -----------
__global__ __launch_bounds__(256) void k_h(const float* __restrict__ X,
                                           const float* __restrict__ W,
                                           const float* __restrict__ Wb,
                                           const float* __restrict__ a1,
                                           const float* __restrict__ a2,
                                           unsigned short* __restrict__ hT,
                                           float* __restrict__ s1,
                                           float* __restrict__ s2) {
    __shared__ char  w_lds[32768];            // [256 o][64 f] bf16, byte ^= (o&7)<<4
    __shared__ char  x_lds[8192];             // [64 n][64 f] bf16, byte ^= (n&7)<<4
    __shared__ float sred1[4][4][16];
    __shared__ float sred2[4][4][16];

    const int tid  = threadIdx.x;
    const int lane = tid & 63;
    const int w    = tid >> 6;
    const int r0   = blockIdx.x * 64;
    const int b    = r0 >> 11;
    const int n0   = r0 & 2047;

    f32x4 acc[4][4];
#pragma unroll
    for (int mt = 0; mt < 4; mt++)
#pragma unroll
        for (int nt = 0; nt < 4; nt++) acc[mt][nt] = (f32x4)0.f;

    for (int kc = 0; kc < 4; kc++) {
        const int f0 = kc * 64;
        __syncthreads();
#pragma unroll
        for (int p = 0; p < 16; p++) {
            int idx = tid + p * 256;
            int o = idx >> 4, fi = idx & 15;
            float4 v = *(const float4*)&W[(size_t)o * Ff + f0 + fi * 4];
            u16x4 pk = {f2bf(v.x), f2bf(v.y), f2bf(v.z), f2bf(v.w)};
            *(u16x4*)(w_lds + ((o * 128 + fi * 8) ^ ((o & 7) << 4))) = pk;
        }
#pragma unroll
        for (int p = 0; p < 4; p++) {
            int idx = tid + p * 256;
            int n = idx >> 4, fi = idx & 15;
            float4 v = *(const float4*)&X[(size_t)(r0 + n) * Ff + f0 + fi * 4];
            u16x4 pk = {f2bf(v.x), f2bf(v.y), f2bf(v.z), f2bf(v.w)};
            *(u16x4*)(x_lds + ((n * 128 + fi * 8) ^ ((n & 7) << 4))) = pk;
        }
        __syncthreads();
#pragma unroll
        for (int kt = 0; kt < 2; kt++) {
            short8 bfr[4];
#pragma unroll
            for (int nt = 0; nt < 4; nt++) {
                int n = nt * 16 + (lane & 15);
                bfr[nt] = *(const short8*)(x_lds + ((n * 128 + kt * 64 + (lane >> 4) * 16) ^ ((n & 7) << 4)));
            }
#pragma unroll
            for (int mt = 0; mt < 4; mt++) {
                int o = w * 64 + mt * 16 + (lane & 15);
                short8 afr = *(const short8*)(w_lds + ((o * 128 + kt * 64 + (lane >> 4) * 16) ^ ((o & 7) << 4)));
#pragma unroll
                for (int nt = 0; nt < 4; nt++)
                    acc[mt][nt] = __builtin_amdgcn_mfma_f32_16x16x32_bf16(afr, bfr[nt], acc[mt][nt], 0, 0, 0);
            }
        }
    }

    float s1p[4] = {0.f, 0.f, 0.f, 0.f};
    float s2p[4] = {0.f, 0.f, 0.f, 0.f};
#pragma unroll
    for (int mt = 0; mt < 4; mt++) {
#pragma unroll
        for (int reg = 0; reg < 4; reg++) {
            int o = w * 64 + mt * 16 + (lane >> 4) * 4 + reg;
            float wb = Wb[o], a1v = a1[o], a2v = a2[o];
#pragma unroll
            for (int nt = 0; nt < 4; nt++) {
                float hv = acc[mt][nt][reg] + wb;
                int n = n0 + nt * 16 + (lane & 15);
                hT[((size_t)(b * Ff + o)) * Nn + n] = f2bf(hv);
                s1p[nt] += hv * a1v;
                s2p[nt] += hv * a2v;
            }
        }
    }
#pragma unroll
    for (int nt = 0; nt < 4; nt++) {
        s1p[nt] += __shfl_xor(s1p[nt], 16); s1p[nt] += __shfl_xor(s1p[nt], 32);
        s2p[nt] += __shfl_xor(s2p[nt], 16); s2p[nt] += __shfl_xor(s2p[nt], 32);
    }
    if (lane < 16) {
#pragma unroll
        for (int nt = 0; nt < 4; nt++) { sred1[w][nt][lane] = s1p[nt]; sred2[w][nt][lane] = s2p[nt]; }
    }
    __syncthreads();
    if (tid < 64) {
        int nt = tid >> 4, col = tid & 15;
        s1[b * Nn + n0 + nt * 16 + col] = sred1[0][nt][col] + sred1[1][nt][col] + sred1[2][nt][col] + sred1[3][nt][col];
    } else if (tid < 128) {
        int t2 = tid - 64;
        int nt = t2 >> 4, col = t2 & 15;
        s2[b * Nn + n0 + nt * 16 + col] = sred2[0][nt][col] + sred2[1][nt][col] + sred2[2][nt][col] + sred2[3][nt][col];
    }
}

// ---------------- k_s2max ----------------
__global__ __launch_bounds__(256) void k_s2max(const float* __restrict__ s2,
                                               float* __restrict__ s2max) {
    int b = blockIdx.x, tid = threadIdx.x;
    float m = -1e30f;
    for (int k = tid; k < Nn; k += 256) m = fmaxf(m, s2[b * Nn + k]);
#pragma unroll
    for (int d = 32; d; d >>= 1) m = fmaxf(m, __shfl_xor(m, d));
    __shared__ float red[4];
    if ((tid & 63) == 0) red[tid >> 6] = m;
    __syncthreads();
    if (tid == 0) s2max[b] = fmaxf(fmaxf(red[0], red[1]), fmaxf(red[2], red[3]));
}

// ---------------- k_attn: scores from mg + bounded softmax + MFMA PV (B direct from L2) ----
// 256 thr / 4 waves; 32 q-rows; j-chunks of 64; 1 barrier/iter; p_lds double-buffered
__global__ __launch_bounds__(256, 3) void k_attn(const unsigned short* __restrict__ hT,
                                                 const float* __restrict__ s1,
                                                 const float* __restrict__ s2,
                                                 const float2* __restrict__ mg,
                                                 const float* __restrict__ gmax,
                                                 const float* __restrict__ s2max,
                                                 const float* __restrict__ ab_p,
                                                 float* __restrict__ out) {
    __shared__ char p_lds[2][4096];     // [32 q][64 k] bf16, byte ^= (q&7)<<4
    __shared__ float linv[32];

    const int bid  = blockIdx.x;
    const int b    = bid & 7;            // XCD slot: hT[b] (1 MB) stays in that XCD's L2
    const int i0   = (bid >> 3) * 32;
    const int tid  = threadIdx.x;
    const int lane = tid & 63;
    const int w    = tid >> 6;
    const float ab  = ab_p[0];
    const float s2m = s2max[b];

    const unsigned short* hTb = hT + (size_t)b * Ff * Nn;

    float s1ab[8], M[8], lsum[8];
#pragma unroll
    for (int r = 0; r < 8; r++) {
        int q = w * 8 + r;
        float sv = s1[b * Nn + i0 + q];
        s1ab[r] = sv + ab;
        float sb = sv + s2m + ab;
        M[r] = (sb > 0.f ? sb : 0.f) + gmax[i0 + q];
        lsum[r] = 0.f;
    }

    f32x4 acc[2][4];
#pragma unroll
    for (int mt = 0; mt < 2; mt++)
#pragma unroll
        for (int nt = 0; nt < 4; nt++) acc[mt][nt] = (f32x4)0.f;

    float mkv[8], ggv[8], s2j;
    short8 Breg[4][2];

    auto load_mg = [&](int t) {
        int j = t * 64 + lane;
        s2j = s2[b * Nn + j];
#pragma unroll
        for (int r = 0; r < 8; r++) {
            float2 v = mg[(size_t)(i0 + w * 8 + r) * Nn + j];
            mkv[r] = v.x;
            ggv[r] = v.y;
        }
    };
    auto load_B = [&](int t) {
#pragma unroll
        for (int nt = 0; nt < 4; nt++) {
            int f = w * 64 + nt * 16 + (lane & 15);
#pragma unroll
            for (int kt = 0; kt < 2; kt++) {
                int j = t * 64 + kt * 32 + (lane >> 4) * 8;
                Breg[nt][kt] = *(const short8*)&hTb[(size_t)f * Nn + j];
            }
        }
    };
    auto scores = [&](int t) {
        char* pb = p_lds[t & 1];
#pragma unroll
        for (int r = 0; r < 8; r++) {
            int q = w * 8 + r;
            float s = s1ab[r] + s2j;
            s = s > 0.f ? s : 0.1f * s;
            float p = __expf(s * mkv[r] + ggv[r] - M[r]);
            lsum[r] += p;
            int byte = (q * 128 + lane * 2) ^ ((q & 7) << 4);
            *(unsigned short*)(pb + byte) = f2bf(p);
        }
    };

    // prologue
    load_mg(0);
    load_B(0);
    scores(0);
    load_mg(1);

    for (int t = 0; t < 32; t++) {
        __syncthreads();                 // p_lds[t&1] writes visible; prev readers done
        char* pb = p_lds[t & 1];
        short8 afr[2][2];
#pragma unroll
        for (int mt = 0; mt < 2; mt++)
#pragma unroll
            for (int kt = 0; kt < 2; kt++) {
                int q = mt * 16 + (lane & 15);
                int byte = (q * 128 + kt * 64 + (lane >> 4) * 16) ^ ((q & 7) << 4);
                afr[mt][kt] = *(const short8*)(pb + byte);
            }
#pragma unroll
        for (int nt = 0; nt < 4; nt++)
#pragma unroll
            for (int kt = 0; kt < 2; kt++) {
                acc[0][nt] = __builtin_amdgcn_mfma_f32_16x16x32_bf16(afr[0][kt], Breg[nt][kt], acc[0][nt], 0, 0, 0);
                acc[1][nt] = __builtin_amdgcn_mfma_f32_16x16x32_bf16(afr[1][kt], Breg[nt][kt], acc[1][nt], 0, 0, 0);
            }
        if (t < 31) {
            load_B(t + 1);               // reuses Breg after last MFMA use
            scores(t + 1);               // consumes mg(t+1), writes p_lds[(t+1)&1]
            if (t < 30) load_mg(t + 2);  // reuses mg regs after scores consumed them
        }
    }

    // denominators
#pragma unroll
    for (int r = 0; r < 8; r++) {
        float ls = lsum[r];
#pragma unroll
        for (int d = 32; d; d >>= 1) ls += __shfl_xor(ls, d);
        if (lane == 0) linv[w * 8 + r] = 1.0f / ls;
    }
    __syncthreads();

#pragma unroll
    for (int mt = 0; mt < 2; mt++) {
#pragma unroll
        for (int reg = 0; reg < 4; reg++) {
            int q = mt * 16 + (lane >> 4) * 4 + reg;
            float inv = linv[q];
            size_t base = ((size_t)(b * Nn + i0 + q)) * Ff + w * 64 + (lane & 15);
#pragma unroll
            for (int nt = 0; nt < 4; nt++) {
                out[base + nt * 16] = acc[mt][nt][reg] * inv;
            }
        }
    }
}

extern "C" void kernel_launch(void* const* d_in, const int* in_sizes, int n_in,
                              void* d_out, int out_size, void* d_ws, size_t ws_size,
                              hipStream_t stream) {
    const float* X    = (const float*)d_in[0];
    const float* Ageo = (const float*)d_in[1];
    const float* Dm   = (const float*)d_in[2];
    const float* Ww   = (const float*)d_in[3];
    const float* Wb   = (const float*)d_in[4];
    const float* a1   = (const float*)d_in[5];
    const float* a2   = (const float*)d_in[6];
    const float* ab   = (const float*)d_in[7];
    const float* thr  = (const float*)d_in[8];
    float* out = (float*)d_out;

    char* ws = (char*)d_ws;
    float2* mg   = (float2*)ws;                                    // N*N float2 = 33.6 MB
    float* gmax  = (float*)(ws + (size_t)Nn * Nn * sizeof(float2)); // N
    float* s2max = gmax  + Nn;                                     // B
    float* s1    = s2max + Bsz;                                    // B*N
    float* s2    = s1    + (size_t)Bsz * Nn;                       // B*N
    unsigned short* hT = (unsigned short*)(s2 + (size_t)Bsz * Nn); // B*F*N bf16

    k_pre<<<Nn, 256, 0, stream>>>(Ageo, Dm, thr, mg, gmax);
    k_h<<<(Bsz * Nn) / 64, 256, 0, stream>>>(X, Ww, Wb, a1, a2, hT, s1, s2);
    k_s2max<<<Bsz, 256, 0, stream>>>(s2, s2max);
    k_attn<<<Nn / 32 * Bsz, 256, 0, stream>>>(hT, s1, s2, mg, gmax, s2max, ab, out);
}

// Round 5
// 96.697 us; speedup vs baseline: 1.2143x; 1.2143x over previous
//
#include <hip/hip_runtime.h>
#include <hip/hip_bf16.h>
#include <hip/hip_fp16.h>
#include <math.h>

#define Bsz 8
#define Nn  2048
#define Ff  256

typedef short short8 __attribute__((ext_vector_type(8)));
typedef float f32x4  __attribute__((ext_vector_type(4)));
typedef unsigned short u16x4 __attribute__((ext_vector_type(4)));
typedef unsigned int uint;

static __device__ __forceinline__ unsigned short f2bf(float v) {
    __hip_bfloat16 b = __float2bfloat16(v);
    return *reinterpret_cast<unsigned short*>(&b);
}
static __device__ __forceinline__ unsigned short f2h(float v) {
    __half h = __float2half(v);
    return *reinterpret_cast<unsigned short*>(&h);
}
static __device__ __forceinline__ float fast_rcp(float x) {
    return __builtin_amdgcn_rcpf(x);
}

// ============ k_preh: fused precompute ============
// blocks [0,256):    h = X@W^T + b -> hT (B,F,N) bf16 ; s1 ; s2   (MFMA-bound)
// blocks [256,2304): mgE[i][j] = pack{mask f16, E=exp(g-gmax_i) bf16}  (memory-bound)
__global__ __launch_bounds__(256) void k_preh(const float* __restrict__ X,
                                              const float* __restrict__ Ageo,
                                              const float* __restrict__ Dm,
                                              const float* __restrict__ W,
                                              const float* __restrict__ Wb,
                                              const float* __restrict__ a1,
                                              const float* __restrict__ a2,
                                              const float* __restrict__ thr_p,
                                              uint* __restrict__ mgE,
                                              unsigned short* __restrict__ hT,
                                              float* __restrict__ s1,
                                              float* __restrict__ s2) {
    __shared__ char smem[43008];   // h: w_lds 32K | x_lds 8K | sred1 1K | sred2 1K ; pre: red[4]
    const int tid  = threadIdx.x;

    if (blockIdx.x >= 256) {
        // ---------- pre-row path ----------
        const int i  = blockIdx.x - 256;
        const int j0 = tid * 8;
        const float c10 = 10.0f * thr_p[0];
        float mk[8], gg[8];
        float m = 0.0f;
#pragma unroll
        for (int p = 0; p < 2; p++) {
            float4 a = *(const float4*)&Ageo[(size_t)i * Nn + j0 + p * 4];
            float4 d = *(const float4*)&Dm[(size_t)i * Nn + j0 + p * 4];
            float av[4] = {a.x, a.y, a.z, a.w};
            float dv[4] = {d.x, d.y, d.z, d.w};
#pragma unroll
            for (int c = 0; c < 4; c++) {
                int idx = p * 4 + c;
                float dd = (j0 + idx == i) ? 1.0f : dv[c];
                float mkv = fast_rcp(1.0f + __expf(c10 - 10.0f * av[c]));
                float g   = mkv * fast_rcp(dd + 1e-5f);
                mk[idx] = mkv;
                gg[idx] = g;
                m = fmaxf(m, g);
            }
        }
#pragma unroll
        for (int d = 32; d; d >>= 1) m = fmaxf(m, __shfl_xor(m, d));
        float* red = (float*)smem;
        if ((tid & 63) == 0) red[tid >> 6] = m;
        __syncthreads();
        float gmax = fmaxf(fmaxf(red[0], red[1]), fmaxf(red[2], red[3]));
        uint u[8];
#pragma unroll
        for (int idx = 0; idx < 8; idx++) {
            float E = __expf(gg[idx] - gmax);
            u[idx] = ((uint)f2bf(E) << 16) | (uint)f2h(mk[idx]);
        }
        uint4* dst = (uint4*)&mgE[(size_t)i * Nn + j0];
        dst[0] = make_uint4(u[0], u[1], u[2], u[3]);
        dst[1] = make_uint4(u[4], u[5], u[6], u[7]);
        return;
    }

    // ---------- h path ----------
    char* w_lds = smem;                                 // [256 o][64 f] bf16, byte ^= (o&7)<<4
    char* x_lds = smem + 32768;                         // [64 n][64 f] bf16, byte ^= (n&7)<<4
    float (*sred1)[4][16] = (float(*)[4][16])(smem + 40960);
    float (*sred2)[4][16] = (float(*)[4][16])(smem + 40960 + 1024);

    const int lane = tid & 63;
    const int w    = tid >> 6;
    const int r0   = blockIdx.x * 64;
    const int b    = r0 >> 11;
    const int n0   = r0 & 2047;

    f32x4 acc[4][4];
#pragma unroll
    for (int mt = 0; mt < 4; mt++)
#pragma unroll
        for (int nt = 0; nt < 4; nt++) acc[mt][nt] = (f32x4)0.f;

    for (int kc = 0; kc < 4; kc++) {
        const int f0 = kc * 64;
        __syncthreads();
#pragma unroll
        for (int p = 0; p < 16; p++) {
            int idx = tid + p * 256;
            int o = idx >> 4, fi = idx & 15;
            float4 v = *(const float4*)&W[(size_t)o * Ff + f0 + fi * 4];
            u16x4 pk = {f2bf(v.x), f2bf(v.y), f2bf(v.z), f2bf(v.w)};
            *(u16x4*)(w_lds + ((o * 128 + fi * 8) ^ ((o & 7) << 4))) = pk;
        }
#pragma unroll
        for (int p = 0; p < 4; p++) {
            int idx = tid + p * 256;
            int n = idx >> 4, fi = idx & 15;
            float4 v = *(const float4*)&X[(size_t)(r0 + n) * Ff + f0 + fi * 4];
            u16x4 pk = {f2bf(v.x), f2bf(v.y), f2bf(v.z), f2bf(v.w)};
            *(u16x4*)(x_lds + ((n * 128 + fi * 8) ^ ((n & 7) << 4))) = pk;
        }
        __syncthreads();
#pragma unroll
        for (int kt = 0; kt < 2; kt++) {
            short8 bfr[4];
#pragma unroll
            for (int nt = 0; nt < 4; nt++) {
                int n = nt * 16 + (lane & 15);
                bfr[nt] = *(const short8*)(x_lds + ((n * 128 + kt * 64 + (lane >> 4) * 16) ^ ((n & 7) << 4)));
            }
#pragma unroll
            for (int mt = 0; mt < 4; mt++) {
                int o = w * 64 + mt * 16 + (lane & 15);
                short8 afr = *(const short8*)(w_lds + ((o * 128 + kt * 64 + (lane >> 4) * 16) ^ ((o & 7) << 4)));
#pragma unroll
                for (int nt = 0; nt < 4; nt++)
                    acc[mt][nt] = __builtin_amdgcn_mfma_f32_16x16x32_bf16(afr, bfr[nt], acc[mt][nt], 0, 0, 0);
            }
        }
    }

    float s1p[4] = {0.f, 0.f, 0.f, 0.f};
    float s2p[4] = {0.f, 0.f, 0.f, 0.f};
#pragma unroll
    for (int mt = 0; mt < 4; mt++) {
#pragma unroll
        for (int reg = 0; reg < 4; reg++) {
            int o = w * 64 + mt * 16 + (lane >> 4) * 4 + reg;
            float wb = Wb[o], a1v = a1[o], a2v = a2[o];
#pragma unroll
            for (int nt = 0; nt < 4; nt++) {
                float hv = acc[mt][nt][reg] + wb;
                int n = n0 + nt * 16 + (lane & 15);
                hT[((size_t)(b * Ff + o)) * Nn + n] = f2bf(hv);
                s1p[nt] += hv * a1v;
                s2p[nt] += hv * a2v;
            }
        }
    }
#pragma unroll
    for (int nt = 0; nt < 4; nt++) {
        s1p[nt] += __shfl_xor(s1p[nt], 16); s1p[nt] += __shfl_xor(s1p[nt], 32);
        s2p[nt] += __shfl_xor(s2p[nt], 16); s2p[nt] += __shfl_xor(s2p[nt], 32);
    }
    if (lane < 16) {
#pragma unroll
        for (int nt = 0; nt < 4; nt++) { sred1[w][nt][lane] = s1p[nt]; sred2[w][nt][lane] = s2p[nt]; }
    }
    __syncthreads();
    if (tid < 64) {
        int nt = tid >> 4, col = tid & 15;
        s1[b * Nn + n0 + nt * 16 + col] = sred1[0][nt][col] + sred1[1][nt][col] + sred1[2][nt][col] + sred1[3][nt][col];
    } else if (tid < 128) {
        int t2 = tid - 64;
        int nt = t2 >> 4, col = t2 & 15;
        s2[b * Nn + n0 + nt * 16 + col] = sred2[0][nt][col] + sred2[1][nt][col] + sred2[2][nt][col] + sred2[3][nt][col];
    }
}

// ---------------- k_s2max ----------------
__global__ __launch_bounds__(256) void k_s2max(const float* __restrict__ s2,
                                               float* __restrict__ s2max) {
    int b = blockIdx.x, tid = threadIdx.x;
    float m = -1e30f;
    for (int k = tid; k < Nn; k += 256) m = fmaxf(m, s2[b * Nn + k]);
#pragma unroll
    for (int d = 32; d; d >>= 1) m = fmaxf(m, __shfl_xor(m, d));
    __shared__ float red[4];
    if ((tid & 63) == 0) red[tid >> 6] = m;
    __syncthreads();
    if (tid == 0) s2max[b] = fmaxf(fmaxf(red[0], red[1]), fmaxf(red[2], red[3]));
}

// ---------------- k_attn: p = exp(leaky(s)*mk - M1) * E ; MFMA PV -----------------
// 512 thr / 8 waves; 32 q-rows; wave w: scores for q=w*4..w*4+3, PV f-slice w*32..w*32+31
__global__ __launch_bounds__(512, 4) void k_attn(const unsigned short* __restrict__ hT,
                                                 const float* __restrict__ s1,
                                                 const float* __restrict__ s2,
                                                 const uint* __restrict__ mgE,
                                                 const float* __restrict__ s2max,
                                                 const float* __restrict__ ab_p,
                                                 float* __restrict__ out) {
    __shared__ char p_lds[2][4096];     // [32 q][64 k] bf16, byte ^= (q&7)<<4
    __shared__ float linv[32];

    const int bid  = blockIdx.x;
    const int b    = bid & 7;            // XCD slot: hT[b] (1 MB) stays in that XCD's L2
    const int i0   = (bid >> 3) * 32;
    const int tid  = threadIdx.x;
    const int lane = tid & 63;
    const int w    = tid >> 6;           // 0..7
    const float ab  = ab_p[0];
    const float s2m = s2max[b];

    const unsigned short* hTb = hT + (size_t)b * Ff * Nn;

    float s1ab[4], M1[4], lsum[4];
#pragma unroll
    for (int r = 0; r < 4; r++) {
        int q = w * 4 + r;
        float sv = s1[b * Nn + i0 + q];
        s1ab[r] = sv + ab;
        float sb = sv + s2m + ab;
        M1[r] = sb > 0.f ? sb : 0.f;
        lsum[r] = 0.f;
    }

    f32x4 acc[2][2];
#pragma unroll
    for (int mt = 0; mt < 2; mt++)
#pragma unroll
        for (int nt = 0; nt < 2; nt++) acc[mt][nt] = (f32x4)0.f;

    uint vmg[4];
    float s2j;
    short8 Breg[2][2];

    auto load_mg = [&](int t) {
        int j = t * 64 + lane;
        s2j = s2[b * Nn + j];
#pragma unroll
        for (int r = 0; r < 4; r++)
            vmg[r] = mgE[(size_t)(i0 + w * 4 + r) * Nn + j];
    };
    auto load_B = [&](int t) {
#pragma unroll
        for (int nt = 0; nt < 2; nt++) {
            int f = w * 32 + nt * 16 + (lane & 15);
#pragma unroll
            for (int kt = 0; kt < 2; kt++) {
                int j = t * 64 + kt * 32 + (lane >> 4) * 8;
                Breg[nt][kt] = *(const short8*)&hTb[(size_t)f * Nn + j];
            }
        }
    };
    auto scores = [&](int t) {
        char* pb = p_lds[t & 1];
#pragma unroll
        for (int r = 0; r < 4; r++) {
            int q = w * 4 + r;
            uint v = vmg[r];
            unsigned short lo = (unsigned short)(v & 0xffffu);
            float mk = __half2float(*reinterpret_cast<__half*>(&lo));
            float E  = __uint_as_float(v & 0xffff0000u);
            float s = s1ab[r] + s2j;
            s = s > 0.f ? s : 0.1f * s;
            float p = __expf(s * mk - M1[r]) * E;
            lsum[r] += p;
            int byte = (q * 128 + lane * 2) ^ ((q & 7) << 4);
            *(unsigned short*)(pb + byte) = f2bf(p);
        }
    };

    // prologue
    load_mg(0);
    load_B(0);
    scores(0);
    load_mg(1);

    for (int t = 0; t < 32; t++) {
        __syncthreads();                 // p_lds[t&1] writes visible; prev readers done
        char* pb = p_lds[t & 1];
        short8 afr[2][2];
#pragma unroll
        for (int mt = 0; mt < 2; mt++)
#pragma unroll
            for (int kt = 0; kt < 2; kt++) {
                int q = mt * 16 + (lane & 15);
                int byte = (q * 128 + kt * 64 + (lane >> 4) * 16) ^ ((q & 7) << 4);
                afr[mt][kt] = *(const short8*)(pb + byte);
            }
#pragma unroll
        for (int nt = 0; nt < 2; nt++)
#pragma unroll
            for (int kt = 0; kt < 2; kt++) {
                acc[0][nt] = __builtin_amdgcn_mfma_f32_16x16x32_bf16(afr[0][kt], Breg[nt][kt], acc[0][nt], 0, 0, 0);
                acc[1][nt] = __builtin_amdgcn_mfma_f32_16x16x32_bf16(afr[1][kt], Breg[nt][kt], acc[1][nt], 0, 0, 0);
            }
        if (t < 31) {
            load_B(t + 1);               // Breg reused after last MFMA
            scores(t + 1);               // consumes vmg(t+1), writes p_lds[(t+1)&1]
            if (t < 30) load_mg(t + 2);  // refill vmg
        }
    }

    // denominators
#pragma unroll
    for (int r = 0; r < 4; r++) {
        float ls = lsum[r];
#pragma unroll
        for (int d = 32; d; d >>= 1) ls += __shfl_xor(ls, d);
        if (lane == 0) linv[w * 4 + r] = 1.0f / ls;
    }
    __syncthreads();

#pragma unroll
    for (int mt = 0; mt < 2; mt++) {
#pragma unroll
        for (int reg = 0; reg < 4; reg++) {
            int q = mt * 16 + (lane >> 4) * 4 + reg;
            float inv = linv[q];
            size_t base = ((size_t)(b * Nn + i0 + q)) * Ff + w * 32 + (lane & 15);
#pragma unroll
            for (int nt = 0; nt < 2; nt++) {
                out[base + nt * 16] = acc[mt][nt][reg] * inv;
            }
        }
    }
}

extern "C" void kernel_launch(void* const* d_in, const int* in_sizes, int n_in,
                              void* d_out, int out_size, void* d_ws, size_t ws_size,
                              hipStream_t stream) {
    const float* X    = (const float*)d_in[0];
    const float* Ageo = (const float*)d_in[1];
    const float* Dm   = (const float*)d_in[2];
    const float* Ww   = (const float*)d_in[3];
    const float* Wb   = (const float*)d_in[4];
    const float* a1   = (const float*)d_in[5];
    const float* a2   = (const float*)d_in[6];
    const float* ab   = (const float*)d_in[7];
    const float* thr  = (const float*)d_in[8];
    float* out = (float*)d_out;

    char* ws = (char*)d_ws;
    uint* mgE    = (uint*)ws;                                       // N*N uint = 16.8 MB
    float* s2max = (float*)(ws + (size_t)Nn * Nn * sizeof(uint));   // B
    float* s1    = s2max + Bsz;                                     // B*N
    float* s2    = s1    + (size_t)Bsz * Nn;                        // B*N
    unsigned short* hT = (unsigned short*)(s2 + (size_t)Bsz * Nn);  // B*F*N bf16

    k_preh<<<256 + Nn, 256, 0, stream>>>(X, Ageo, Dm, Ww, Wb, a1, a2, thr, mgE, hT, s1, s2);
    k_s2max<<<Bsz, 256, 0, stream>>>(s2, s2max);
    k_attn<<<Nn / 32 * Bsz, 512, 0, stream>>>(hT, s1, s2, mgE, s2max, ab, out);
}

// Round 6
// 87.365 us; speedup vs baseline: 1.3441x; 1.1068x over previous
//
#include <hip/hip_runtime.h>
#include <hip/hip_bf16.h>
#include <hip/hip_fp16.h>
#include <math.h>

#define Bsz 8
#define Nn  2048
#define Ff  256

typedef short short8 __attribute__((ext_vector_type(8)));
typedef float f32x4  __attribute__((ext_vector_type(4)));
typedef unsigned short u16x4 __attribute__((ext_vector_type(4)));
typedef unsigned int uint;

static __device__ __forceinline__ unsigned short f2bf(float v) {
    __hip_bfloat16 b = __float2bfloat16(v);
    return *reinterpret_cast<unsigned short*>(&b);
}
static __device__ __forceinline__ unsigned short f2h(float v) {
    __half h = __float2half(v);
    return *reinterpret_cast<unsigned short*>(&h);
}
static __device__ __forceinline__ float fast_rcp(float x) {
    return __builtin_amdgcn_rcpf(x);
}

// ============ k_preh: fused precompute ============
// blocks [0,256):    h = X@W^T + b -> hT (B,F,N) bf16 ; s1 ; s2 ; atomicMax s2max
// blocks [256,2304): mgE[i][j] = pack{mask f16, E=exp(g-gmax_i) bf16}
__global__ __launch_bounds__(256) void k_preh(const float* __restrict__ X,
                                              const float* __restrict__ Ageo,
                                              const float* __restrict__ Dm,
                                              const float* __restrict__ W,
                                              const float* __restrict__ Wb,
                                              const float* __restrict__ a1,
                                              const float* __restrict__ a2,
                                              const float* __restrict__ thr_p,
                                              uint* __restrict__ mgE,
                                              unsigned short* __restrict__ hT,
                                              float* __restrict__ s1,
                                              float* __restrict__ s2,
                                              uint* __restrict__ s2u) {
    __shared__ char smem[43008];
    const int tid  = threadIdx.x;

    if (blockIdx.x >= 256) {
        // ---------- pre-row path ----------
        const int i  = blockIdx.x - 256;
        const int j0 = tid * 8;
        const float c10 = 10.0f * thr_p[0];
        float mk[8], gg[8];
        float m = 0.0f;
#pragma unroll
        for (int p = 0; p < 2; p++) {
            float4 a = *(const float4*)&Ageo[(size_t)i * Nn + j0 + p * 4];
            float4 d = *(const float4*)&Dm[(size_t)i * Nn + j0 + p * 4];
            float av[4] = {a.x, a.y, a.z, a.w};
            float dv[4] = {d.x, d.y, d.z, d.w};
#pragma unroll
            for (int c = 0; c < 4; c++) {
                int idx = p * 4 + c;
                float dd = (j0 + idx == i) ? 1.0f : dv[c];
                float mkv = fast_rcp(1.0f + __expf(c10 - 10.0f * av[c]));
                float g   = mkv * fast_rcp(dd + 1e-5f);
                mk[idx] = mkv;
                gg[idx] = g;
                m = fmaxf(m, g);
            }
        }
#pragma unroll
        for (int d = 32; d; d >>= 1) m = fmaxf(m, __shfl_xor(m, d));
        float* red = (float*)smem;
        if ((tid & 63) == 0) red[tid >> 6] = m;
        __syncthreads();
        float gmax = fmaxf(fmaxf(red[0], red[1]), fmaxf(red[2], red[3]));
        uint u[8];
#pragma unroll
        for (int idx = 0; idx < 8; idx++) {
            float E = __expf(gg[idx] - gmax);
            u[idx] = ((uint)f2bf(E) << 16) | (uint)f2h(mk[idx]);
        }
        uint4* dst = (uint4*)&mgE[(size_t)i * Nn + j0];
        dst[0] = make_uint4(u[0], u[1], u[2], u[3]);
        dst[1] = make_uint4(u[4], u[5], u[6], u[7]);
        return;
    }

    // ---------- h path ----------
    char* w_lds = smem;                                 // [256 o][64 f] bf16, byte ^= (o&7)<<4
    char* x_lds = smem + 32768;                         // [64 n][64 f] bf16, byte ^= (n&7)<<4
    float (*sred1)[4][16] = (float(*)[4][16])(smem + 40960);
    float (*sred2)[4][16] = (float(*)[4][16])(smem + 40960 + 1024);

    const int lane = tid & 63;
    const int w    = tid >> 6;
    const int r0   = blockIdx.x * 64;
    const int b    = r0 >> 11;
    const int n0   = r0 & 2047;

    f32x4 acc[4][4];
#pragma unroll
    for (int mt = 0; mt < 4; mt++)
#pragma unroll
        for (int nt = 0; nt < 4; nt++) acc[mt][nt] = (f32x4)0.f;

    for (int kc = 0; kc < 4; kc++) {
        const int f0 = kc * 64;
        __syncthreads();
#pragma unroll
        for (int p = 0; p < 16; p++) {
            int idx = tid + p * 256;
            int o = idx >> 4, fi = idx & 15;
            float4 v = *(const float4*)&W[(size_t)o * Ff + f0 + fi * 4];
            u16x4 pk = {f2bf(v.x), f2bf(v.y), f2bf(v.z), f2bf(v.w)};
            *(u16x4*)(w_lds + ((o * 128 + fi * 8) ^ ((o & 7) << 4))) = pk;
        }
#pragma unroll
        for (int p = 0; p < 4; p++) {
            int idx = tid + p * 256;
            int n = idx >> 4, fi = idx & 15;
            float4 v = *(const float4*)&X[(size_t)(r0 + n) * Ff + f0 + fi * 4];
            u16x4 pk = {f2bf(v.x), f2bf(v.y), f2bf(v.z), f2bf(v.w)};
            *(u16x4*)(x_lds + ((n * 128 + fi * 8) ^ ((n & 7) << 4))) = pk;
        }
        __syncthreads();
#pragma unroll
        for (int kt = 0; kt < 2; kt++) {
            short8 bfr[4];
#pragma unroll
            for (int nt = 0; nt < 4; nt++) {
                int n = nt * 16 + (lane & 15);
                bfr[nt] = *(const short8*)(x_lds + ((n * 128 + kt * 64 + (lane >> 4) * 16) ^ ((n & 7) << 4)));
            }
#pragma unroll
            for (int mt = 0; mt < 4; mt++) {
                int o = w * 64 + mt * 16 + (lane & 15);
                short8 afr = *(const short8*)(w_lds + ((o * 128 + kt * 64 + (lane >> 4) * 16) ^ ((o & 7) << 4)));
#pragma unroll
                for (int nt = 0; nt < 4; nt++)
                    acc[mt][nt] = __builtin_amdgcn_mfma_f32_16x16x32_bf16(afr, bfr[nt], acc[mt][nt], 0, 0, 0);
            }
        }
    }

    float s1p[4] = {0.f, 0.f, 0.f, 0.f};
    float s2p[4] = {0.f, 0.f, 0.f, 0.f};
#pragma unroll
    for (int mt = 0; mt < 4; mt++) {
#pragma unroll
        for (int reg = 0; reg < 4; reg++) {
            int o = w * 64 + mt * 16 + (lane >> 4) * 4 + reg;
            float wb = Wb[o], a1v = a1[o], a2v = a2[o];
#pragma unroll
            for (int nt = 0; nt < 4; nt++) {
                float hv = acc[mt][nt][reg] + wb;
                int n = n0 + nt * 16 + (lane & 15);
                hT[((size_t)(b * Ff + o)) * Nn + n] = f2bf(hv);
                s1p[nt] += hv * a1v;
                s2p[nt] += hv * a2v;
            }
        }
    }
#pragma unroll
    for (int nt = 0; nt < 4; nt++) {
        s1p[nt] += __shfl_xor(s1p[nt], 16); s1p[nt] += __shfl_xor(s1p[nt], 32);
        s2p[nt] += __shfl_xor(s2p[nt], 16); s2p[nt] += __shfl_xor(s2p[nt], 32);
    }
    if (lane < 16) {
#pragma unroll
        for (int nt = 0; nt < 4; nt++) { sred1[w][nt][lane] = s1p[nt]; sred2[w][nt][lane] = s2p[nt]; }
    }
    __syncthreads();
    if (tid < 64) {
        int nt = tid >> 4, col = tid & 15;
        s1[b * Nn + n0 + nt * 16 + col] = sred1[0][nt][col] + sred1[1][nt][col] + sred1[2][nt][col] + sred1[3][nt][col];
    } else if (tid < 128) {
        int t2 = tid - 64;
        int nt = t2 >> 4, col = t2 & 15;
        float v = sred2[0][nt][col] + sred2[1][nt][col] + sred2[2][nt][col] + sred2[3][nt][col];
        s2[b * Nn + n0 + nt * 16 + col] = v;
        // wave-level max -> one atomic per block (flipped-uint encoding, monotone)
#pragma unroll
        for (int d = 32; d; d >>= 1) v = fmaxf(v, __shfl_xor(v, d));
        if (tid == 64) {
            uint bits = __float_as_uint(v);
            uint key  = (bits & 0x80000000u) ? ~bits : (bits | 0x80000000u);
            atomicMax(&s2u[b], key);
        }
    }
}

// ---------------- k_attn: phase-split scores + PV ----------------
// 256 blocks x 512 thr; block = (b, 64 q-rows); j processed in 2 halves of 1024
// phase 1: scores -> p_lds (swizzled bf16), no barriers, depth-2 mg prefetch
// phase 2: PV GEMM: A from p_lds, B (hT) from L2, no barriers
__global__ __launch_bounds__(512) void k_attn(const unsigned short* __restrict__ hT,
                                              const float* __restrict__ s1,
                                              const float* __restrict__ s2b_,
                                              const uint* __restrict__ mgE,
                                              const uint* __restrict__ s2u,
                                              const float* __restrict__ ab_p,
                                              float* __restrict__ out) {
    __shared__ char p_lds[64 * 2048];   // [64 q][1024 j] bf16, byte ^= (q&7)<<4
    __shared__ float linv[64];

    const int bid  = blockIdx.x;
    const int b    = bid & 7;                    // XCD slot: hT[b] L2-resident
    const int qb   = bid >> 3;                   // 0..31
    const int i0   = ((qb + b * 4) & 31) * 64;   // stagger row-starts across XCDs
    const int tid  = threadIdx.x;
    const int lane = tid & 63;
    const int w    = tid >> 6;                   // 0..7
    const float ab = ab_p[0];

    uint key = s2u[b];
    uint sbits = (key & 0x80000000u) ? (key ^ 0x80000000u) : ~key;
    const float s2m = __uint_as_float(sbits);

    const unsigned short* hTb = hT + (size_t)b * Ff * Nn;
    const float* s2b = s2b_ + b * Nn;

    float s1ab[8], M1[8], lsum[8];
#pragma unroll
    for (int r = 0; r < 8; r++) {
        int gi = i0 + w * 8 + r;
        float sv = s1[b * Nn + gi];
        s1ab[r] = sv + ab;
        float sb = sv + s2m + ab;
        M1[r] = sb > 0.f ? sb : 0.f;
        lsum[r] = 0.f;
    }

    f32x4 acc[4][2];
#pragma unroll
    for (int mt = 0; mt < 4; mt++)
#pragma unroll
        for (int nt = 0; nt < 2; nt++) acc[mt][nt] = (f32x4)0.f;

    uint2  mgv[2][8];
    float2 s2v[2];

    for (int ro = 0; ro < 2; ro++) {
        // ================= phase 1: scores =================
        auto p1load = [&](int it, int buf) {
            int j = ro * 1024 + it * 128 + lane * 2;
            s2v[buf] = *(const float2*)&s2b[j];
#pragma unroll
            for (int r = 0; r < 8; r++)
                mgv[buf][r] = *(const uint2*)&mgE[(size_t)(i0 + w * 8 + r) * Nn + j];
        };
        p1load(0, 0);
        p1load(1, 1);
#pragma unroll
        for (int it = 0; it < 8; it++) {
            int buf = it & 1;
            int jl = (it * 128 + lane * 2) & 1023;       // local j within half
            float s2j0 = s2v[buf].x, s2j1 = s2v[buf].y;
#pragma unroll
            for (int r = 0; r < 8; r++) {
                int q = w * 8 + r;
                uint2 v = mgv[buf][r];
                // elem 0
                unsigned short lo0 = (unsigned short)(v.x & 0xffffu);
                float mk0 = __half2float(*reinterpret_cast<__half*>(&lo0));
                float E0  = __uint_as_float(v.x & 0xffff0000u);
                float sA = s1ab[r] + s2j0;
                sA = fmaxf(sA, 0.1f * sA);
                float p0 = __expf(sA * mk0 - M1[r]) * E0;
                // elem 1
                unsigned short lo1 = (unsigned short)(v.y & 0xffffu);
                float mk1 = __half2float(*reinterpret_cast<__half*>(&lo1));
                float E1  = __uint_as_float(v.y & 0xffff0000u);
                float sB = s1ab[r] + s2j1;
                sB = fmaxf(sB, 0.1f * sB);
                float p1 = __expf(sB * mk1 - M1[r]) * E1;
                lsum[r] += p0 + p1;
                uint pk = ((uint)f2bf(p1) << 16) | (uint)f2bf(p0);
                *(uint*)(p_lds + ((q * 2048 + jl * 2) ^ ((q & 7) << 4))) = pk;
            }
            if (it + 2 < 8) p1load(it + 2, buf);
        }

        if (ro == 1) {
            // finalize denominators (lsum complete) before the barrier
#pragma unroll
            for (int r = 0; r < 8; r++) {
                float ls = lsum[r];
#pragma unroll
                for (int d = 32; d; d >>= 1) ls += __shfl_xor(ls, d);
                if (lane == 0) linv[w * 8 + r] = 1.0f / ls;
            }
        }
        __syncthreads();          // p_lds visible (and linv on ro==1)

        // ================= phase 2: PV GEMM =================
#pragma unroll 2
        for (int kt = 0; kt < 32; kt++) {
            int jl = kt * 64;                      // local byte-base/2... (32 keys * 2B)
            int jg = ro * 1024 + kt * 32;
            short8 afr[4];
#pragma unroll
            for (int mt = 0; mt < 4; mt++) {
                int q = mt * 16 + (lane & 15);
                afr[mt] = *(const short8*)(p_lds + ((q * 2048 + jl + (lane >> 4) * 16) ^ ((q & 7) << 4)));
            }
            short8 bfr[2];
#pragma unroll
            for (int nt = 0; nt < 2; nt++) {
                int f = w * 32 + nt * 16 + (lane & 15);
                bfr[nt] = *(const short8*)&hTb[(size_t)f * Nn + jg + (lane >> 4) * 8];
            }
#pragma unroll
            for (int mt = 0; mt < 4; mt++)
#pragma unroll
                for (int nt = 0; nt < 2; nt++)
                    acc[mt][nt] = __builtin_amdgcn_mfma_f32_16x16x32_bf16(afr[mt], bfr[nt], acc[mt][nt], 0, 0, 0);
        }
        if (ro == 0) __syncthreads();   // protect p_lds before half-1 overwrites
    }

    // epilogue: scale by 1/denominator, write out
#pragma unroll
    for (int mt = 0; mt < 4; mt++) {
#pragma unroll
        for (int reg = 0; reg < 4; reg++) {
            int q = mt * 16 + (lane >> 4) * 4 + reg;
            float inv = linv[q];
            size_t base = ((size_t)(b * Nn + i0 + q)) * Ff + w * 32 + (lane & 15);
#pragma unroll
            for (int nt = 0; nt < 2; nt++) {
                out[base + nt * 16] = acc[mt][nt][reg] * inv;
            }
        }
    }
}

extern "C" void kernel_launch(void* const* d_in, const int* in_sizes, int n_in,
                              void* d_out, int out_size, void* d_ws, size_t ws_size,
                              hipStream_t stream) {
    const float* X    = (const float*)d_in[0];
    const float* Ageo = (const float*)d_in[1];
    const float* Dm   = (const float*)d_in[2];
    const float* Ww   = (const float*)d_in[3];
    const float* Wb   = (const float*)d_in[4];
    const float* a1   = (const float*)d_in[5];
    const float* a2   = (const float*)d_in[6];
    const float* ab   = (const float*)d_in[7];
    const float* thr  = (const float*)d_in[8];
    float* out = (float*)d_out;

    char* ws = (char*)d_ws;
    uint* mgE    = (uint*)ws;                                        // N*N uint = 16.8 MB
    uint* s2u    = (uint*)(ws + (size_t)Nn * Nn * sizeof(uint));     // 16 (padded)
    float* s1    = (float*)(s2u + 16);                               // B*N
    float* s2    = s1 + (size_t)Bsz * Nn;                            // B*N
    unsigned short* hT = (unsigned short*)(s2 + (size_t)Bsz * Nn);   // B*F*N bf16

    hipMemsetAsync(s2u, 0, 16 * sizeof(uint), stream);
    k_preh<<<256 + Nn, 256, 0, stream>>>(X, Ageo, Dm, Ww, Wb, a1, a2, thr, mgE, hT, s1, s2, s2u);
    k_attn<<<256, 512, 0, stream>>>(hT, s1, s2, mgE, s2u, ab, out);
}